// Round 1
// baseline (632.741 us; speedup 1.0000x reference)
//
#include <hip/hip_runtime.h>
#include <hip/hip_bf16.h>
#include <cstdint>

#define NN 256
#define NB 4
#define OC 128

using bf16x8_t = __attribute__((ext_vector_type(8))) __bf16;
using f32x4_t  = __attribute__((ext_vector_type(4))) float;

typedef const __attribute__((address_space(1))) uint8_t* gptr1_t;
typedef __attribute__((address_space(3))) uint8_t* lptr3_t;

__device__ __forceinline__ void async_load16(const void* g, void* l) {
  __builtin_amdgcn_global_load_lds((gptr1_t)g, (lptr3_t)l, 16, 0, 0);
}

__device__ __forceinline__ float sigf(float x) {
  return 1.0f / (1.0f + __expf(-x));
}

__device__ __forceinline__ uint16_t f2bf_rne(float f) {
  uint32_t u = __float_as_uint(f);
  uint32_t r = (u + 0x7fffu + ((u >> 16) & 1u)) >> 16;
  return (uint16_t)r;
}

// ---------------------------------------------------------------------------
// reduce2 for layer 0: fp32 input [B,n,n,64] -> r2 [B,n,128] fp32, plus bf16
// copy of x2 (GEMM A operand). 4 channels/thread via float4.
// ---------------------------------------------------------------------------
__global__ __launch_bounds__(256) void reduce2_l0_kernel(
    const float* __restrict__ x2, float* __restrict__ r2,
    uint16_t* __restrict__ x2bf) {
  const int bid = blockIdx.x;            // b*256 + i
  const int b = bid >> 8, i = bid & 255;
  const int tid = threadIdx.x;
  const int q = tid & 15, s = tid >> 4;  // 16 quads, 16 stripes
  const size_t rowbase = ((size_t)(b * NN + i) * NN) * 64 + q * 4;
  float mx0 = 0.f, mx1 = 0.f, mx2 = 0.f, mx3 = 0.f;
  float mn0 = 1.f, mn1 = 1.f, mn2 = 1.f, mn3 = 1.f;
  for (int j = s; j < NN; j += 16) {
    const float4 x = *(const float4*)(x2 + rowbase + (size_t)j * 64);
    uint2 pk;
    pk.x = (uint32_t)f2bf_rne(x.x) | ((uint32_t)f2bf_rne(x.y) << 16);
    pk.y = (uint32_t)f2bf_rne(x.z) | ((uint32_t)f2bf_rne(x.w) << 16);
    *(uint2*)(x2bf + rowbase + (size_t)j * 64) = pk;
    if (j != i) {
      mx0 = fmaxf(mx0, x.x); mx1 = fmaxf(mx1, x.y);
      mx2 = fmaxf(mx2, x.z); mx3 = fmaxf(mx3, x.w);
      mn0 = fminf(mn0, x.x); mn1 = fminf(mn1, x.y);
      mn2 = fminf(mn2, x.z); mn3 = fminf(mn3, x.w);
    }
  }
  __shared__ float4 smx[256], smn[256];
  smx[tid] = make_float4(mx0, mx1, mx2, mx3);
  smn[tid] = make_float4(mn0, mn1, mn2, mn3);
  __syncthreads();
  if (s == 0) {
    for (int ss = 1; ss < 16; ++ss) {
      float4 a = smx[q + ss * 16], c = smn[q + ss * 16];
      mx0 = fmaxf(mx0, a.x); mx1 = fmaxf(mx1, a.y);
      mx2 = fmaxf(mx2, a.z); mx3 = fmaxf(mx3, a.w);
      mn0 = fminf(mn0, c.x); mn1 = fminf(mn1, c.y);
      mn2 = fminf(mn2, c.z); mn3 = fminf(mn3, c.w);
    }
    float* r = r2 + (size_t)(b * NN + i) * 128;
    r[q * 4 + 0] = mx0; r[q * 4 + 1] = mx1; r[q * 4 + 2] = mx2; r[q * 4 + 3] = mx3;
    r[64 + q * 4 + 0] = mn0; r[64 + q * 4 + 1] = mn1;
    r[64 + q * 4 + 2] = mn2; r[64 + q * 4 + 3] = mn3;
  }
}

// ---------------------------------------------------------------------------
// reduce2 for layers 1/2: bf16 input [B,n,n,128] -> r2 [B,n,256] fp32.
// 4 channels/thread via uint2 (4 bf16).
// ---------------------------------------------------------------------------
__global__ __launch_bounds__(256) void reduce2_bf_kernel(
    const __hip_bfloat16* __restrict__ f2, float* __restrict__ r2) {
  const int bid = blockIdx.x;
  const int b = bid >> 8, i = bid & 255;
  const int tid = threadIdx.x;
  const int q = tid & 31, s = tid >> 5;  // 32 quads, 8 stripes
  const size_t rowbase = ((size_t)(b * NN + i) * NN) * 128 + q * 4;
  float mx0 = 0.f, mx1 = 0.f, mx2 = 0.f, mx3 = 0.f;
  float mn0 = 1.f, mn1 = 1.f, mn2 = 1.f, mn3 = 1.f;
  for (int j = s; j < NN; j += 8) {
    const uint2 w = *(const uint2*)(f2 + rowbase + (size_t)j * 128);
    float v0 = __uint_as_float(w.x << 16);
    float v1 = __uint_as_float(w.x & 0xffff0000u);
    float v2 = __uint_as_float(w.y << 16);
    float v3 = __uint_as_float(w.y & 0xffff0000u);
    if (j != i) {
      mx0 = fmaxf(mx0, v0); mx1 = fmaxf(mx1, v1);
      mx2 = fmaxf(mx2, v2); mx3 = fmaxf(mx3, v3);
      mn0 = fminf(mn0, v0); mn1 = fminf(mn1, v1);
      mn2 = fminf(mn2, v2); mn3 = fminf(mn3, v3);
    }
  }
  __shared__ float4 smx[256], smn[256];
  smx[tid] = make_float4(mx0, mx1, mx2, mx3);
  smn[tid] = make_float4(mn0, mn1, mn2, mn3);
  __syncthreads();
  if (s == 0) {
    for (int ss = 1; ss < 8; ++ss) {
      float4 a = smx[q + ss * 32], c = smn[q + ss * 32];
      mx0 = fmaxf(mx0, a.x); mx1 = fmaxf(mx1, a.y);
      mx2 = fmaxf(mx2, a.z); mx3 = fmaxf(mx3, a.w);
      mn0 = fminf(mn0, c.x); mn1 = fminf(mn1, c.y);
      mn2 = fminf(mn2, c.z); mn3 = fminf(mn3, c.w);
    }
    float* r = r2 + (size_t)(b * NN + i) * 256;
    r[q * 4 + 0] = mx0; r[q * 4 + 1] = mx1; r[q * 4 + 2] = mx2; r[q * 4 + 3] = mx3;
    r[128 + q * 4 + 0] = mn0; r[128 + q * 4 + 1] = mn1;
    r[128 + q * 4 + 2] = mn2; r[128 + q * 4 + 3] = mn3;
  }
}

// ---------------------------------------------------------------------------
// o0: g0 = [f0, max_n f1, min_n f1]; f0out = sigmoid(g0 @ W0 + b0). One block
// per batch element.
// ---------------------------------------------------------------------------
template <int D0, int D1>
__global__ __launch_bounds__(256) void o0_kernel(
    const float* __restrict__ f0, const float* __restrict__ f1,
    const float* __restrict__ W0, const float* __restrict__ b0,
    float* __restrict__ f0out) {
  constexpr int FIN = D0 + 2 * D1;
  constexpr int S = 256 / D1;
  const int b = blockIdx.x;
  const int tid = threadIdx.x;
  const int c = tid & (D1 - 1), s = tid / D1;
  __shared__ float g0[FIN];
  __shared__ float smx[256], smn[256];
  float mx = -1e30f, mn = 1e30f;
  const float* f1b = f1 + (size_t)b * NN * D1;
  for (int j = s; j < NN; j += S) {
    float x = f1b[(size_t)j * D1 + c];
    mx = fmaxf(mx, x); mn = fminf(mn, x);
  }
  smx[tid] = mx; smn[tid] = mn;
  __syncthreads();
  if (s == 0) {
    for (int ss = 1; ss < S; ++ss) {
      mx = fmaxf(mx, smx[c + ss * D1]);
      mn = fminf(mn, smn[c + ss * D1]);
    }
    g0[D0 + c] = mx;
    g0[D0 + D1 + c] = mn;
  }
  if (tid < D0) g0[tid] = f0[b * D0 + tid];
  __syncthreads();
  if (tid < OC) {
    float acc = b0[tid];
#pragma unroll 8
    for (int k = 0; k < FIN; ++k) acc += g0[k] * W0[k * OC + tid];
    f0out[b * OC + tid] = sigf(acc);
  }
}

// ---------------------------------------------------------------------------
// u/v: u[b,i,c] = f1[b,i]·Wa[:,c] + b2[c]; v[b,i,c] = f1[b,i]·Wc[:,c].
// Wa = W2 rows [0,d1), Wc = W2 rows [d1+d2, d1+d2+d1). One block per (b,i).
// ---------------------------------------------------------------------------
template <int D1, int D2>
__global__ __launch_bounds__(128) void uv_kernel(
    const float* __restrict__ f1, const float* __restrict__ W2,
    const float* __restrict__ b2, float* __restrict__ u, float* __restrict__ v) {
  const int bi = blockIdx.x;
  const int c = threadIdx.x;
  const float* row = f1 + (size_t)bi * D1;
  float au = b2[c], av = 0.f;
#pragma unroll 8
  for (int k = 0; k < D1; ++k) {
    float x = row[k];
    au += x * W2[k * OC + c];
    av += x * W2[(D1 + D2 + k) * OC + c];
  }
  u[(size_t)bi * OC + c] = au;
  v[(size_t)bi * OC + c] = av;
}

// ---------------------------------------------------------------------------
// o1: g1 = [f0, f1[b,i], r2[b,i]]; f1out = sigmoid(g1 @ W1 + b1). One block
// per (b,i), 128 threads (one per output channel).
// ---------------------------------------------------------------------------
template <int D0, int D1, int D2>
__global__ __launch_bounds__(128) void o1_kernel(
    const float* __restrict__ f0, const float* __restrict__ f1,
    const float* __restrict__ r2, const float* __restrict__ W1,
    const float* __restrict__ b1, float* __restrict__ f1out) {
  constexpr int FIN = D0 + D1 + 2 * D2;
  const int bi = blockIdx.x;
  const int b = bi >> 8;
  const int tid = threadIdx.x;
  __shared__ float g1[FIN];
  for (int k = tid; k < FIN; k += 128) {
    float x;
    if (k < D0) x = f0[b * D0 + k];
    else if (k < D0 + D1) x = f1[(size_t)bi * D1 + (k - D0)];
    else x = r2[(size_t)bi * (2 * D2) + (k - D0 - D1)];
    g1[k] = x;
  }
  __syncthreads();
  float acc = b1[tid];
#pragma unroll 8
  for (int k = 0; k < FIN; ++k) acc += g1[k] * W1[k * OC + tid];
  f1out[(size_t)bi * OC + tid] = sigf(acc);
}

// ---------------------------------------------------------------------------
// prep: Wt[n][k] bf16 where k<d2 -> W2[d1+k][n] (Wb), else W2[2*d1+d2+k-d2][n]
// (Wd). Pre-transposed so gemm2's global_load_lds gets 16B-contiguous rows.
// ---------------------------------------------------------------------------
__global__ void prep_wt_kernel(const float* __restrict__ W2,
                               uint16_t* __restrict__ Wt, int d1, int d2) {
  const int K = 2 * d2;
  const int idx = blockIdx.x * 256 + threadIdx.x;
  if (idx >= OC * K) return;
  const int nn = idx / K, k = idx - nn * K;
  const int row = (k < d2) ? (d1 + k) : (2 * d1 + d2 + (k - d2));
  Wt[idx] = f2bf_rne(W2[row * OC + nn]);
}

// ---------------------------------------------------------------------------
// Big order-2 GEMM. Block = (b, i, j-tile of 128): output 128 rows x 128 ch.
// acc[j,c] = sum_k f2[b,i,j,k]*Wb[k,c] + sum_k f2[b,j,i,k]*Wd[k,c]
// out = sigmoid(acc + u[b,i,c] + v[b,j,c]).
// A and W staged via global_load_lds (16B/lane) into MFMA-fragment-ordered
// LDS units of 1 KiB (16 rows x 32 k), so ds_read_b128 is linear.
// ---------------------------------------------------------------------------
__device__ __forceinline__ void store_val(float* p, float x) { *p = x; }
__device__ __forceinline__ void store_val(__hip_bfloat16* p, float x) {
  *(uint16_t*)p = f2bf_rne(x);
}

template <int D2, typename OUT_T>
__global__ __launch_bounds__(256, 2) void gemm2_kernel(
    const __hip_bfloat16* __restrict__ f2, const uint16_t* __restrict__ Wt,
    const float* __restrict__ u, const float* __restrict__ v,
    OUT_T* __restrict__ out) {
  constexpr int K = 2 * D2;
  constexpr int NCH = K / 64;
  const int bid = blockIdx.x;
  const int jt = bid & 1, i = (bid >> 1) & 255, b = bid >> 9;
  const int j0 = jt * 128;
  const int tid = threadIdx.x;
  const int wv = tid >> 6, lane = tid & 63;
  const int wr = wv >> 1, wc = wv & 1;
  const int l15 = lane & 15, l4 = lane >> 4;

  __shared__ __align__(16) uint8_t ldsA[16384];
  __shared__ __align__(16) uint8_t ldsW[16384];

  const __hip_bfloat16* A1 = f2 + ((size_t)(b * NN + i) * NN + j0) * D2;
  const __hip_bfloat16* A2 = f2 + ((size_t)(b * NN + j0) * NN + i) * D2;

  f32x4_t acc[4][4];
#pragma unroll
  for (int a = 0; a < 4; ++a)
#pragma unroll
    for (int q = 0; q < 4; ++q) acc[a][q] = (f32x4_t){0.f, 0.f, 0.f, 0.f};

  for (int c = 0; c < NCH; ++c) {
    const int kbg = c * 64;
    const bool second = (kbg >= D2);
    const __hip_bfloat16* Ab = second ? A2 : A1;
    const size_t rstride = second ? (size_t)NN * D2 : (size_t)D2;
    const int kbase = second ? (kbg - D2) : kbg;
#pragma unroll
    for (int q = 0; q < 4; ++q) {  // A units: id = (ks*8 + mi)
      const int id = wv * 4 + q;
      const int mi = id & 7, ks = id >> 3;
      const int row = mi * 16 + l15;
      const int kk = ks * 32 + l4 * 8;
      async_load16(Ab + (size_t)row * rstride + kbase + kk, ldsA + id * 1024);
    }
#pragma unroll
    for (int q = 0; q < 4; ++q) {  // W units: id = (ks*8 + ni)
      const int id = wv * 4 + q;
      const int ni = id & 7, ks = id >> 3;
      const int nn2 = ni * 16 + l15;
      const int kk = ks * 32 + l4 * 8;
      async_load16(Wt + (size_t)nn2 * K + kbg + kk, ldsW + id * 1024);
    }
    __syncthreads();
#pragma unroll
    for (int ks = 0; ks < 2; ++ks) {
      bf16x8_t Af[4], Bf[4];
#pragma unroll
      for (int a = 0; a < 4; ++a)
        Af[a] = *(const bf16x8_t*)(ldsA + ((ks * 8 + wr * 4 + a) << 10) + (lane << 4));
#pragma unroll
      for (int q = 0; q < 4; ++q)
        Bf[q] = *(const bf16x8_t*)(ldsW + ((ks * 8 + wc * 4 + q) << 10) + (lane << 4));
#pragma unroll
      for (int a = 0; a < 4; ++a)
#pragma unroll
        for (int q = 0; q < 4; ++q)
          acc[a][q] = __builtin_amdgcn_mfma_f32_16x16x32_bf16(Af[a], Bf[q],
                                                              acc[a][q], 0, 0, 0);
    }
    __syncthreads();
  }

  // epilogue: C/D layout col = lane&15, row = (lane>>4)*4 + reg
  const size_t uo = (size_t)(b * NN + i) * OC;
  float uval[4];
#pragma unroll
  for (int q = 0; q < 4; ++q) uval[q] = u[uo + wc * 64 + q * 16 + l15];
  const size_t obase = ((size_t)(b * NN + i) * NN + j0) * OC;
  const size_t vbase = (size_t)(b * NN + j0) * OC;
#pragma unroll
  for (int a = 0; a < 4; ++a) {
    const int rowb = wr * 64 + a * 16 + l4 * 4;
#pragma unroll
    for (int r = 0; r < 4; ++r) {
      const int j = rowb + r;
#pragma unroll
      for (int q = 0; q < 4; ++q) {
        const int col = wc * 64 + q * 16 + l15;
        const float x = acc[a][q][r] + uval[q] + v[vbase + (size_t)j * OC + col];
        store_val(out + obase + (size_t)j * OC + col, sigf(x));
      }
    }
  }
}

// ---------------------------------------------------------------------------
extern "C" void kernel_launch(void* const* d_in, const int* in_sizes, int n_in,
                              void* d_out, int out_size, void* d_ws,
                              size_t ws_size, hipStream_t stream) {
  const float* x0 = (const float*)d_in[0];
  const float* x1 = (const float*)d_in[1];
  const float* x2 = (const float*)d_in[2];
  const float *Wp[3][3], *bp[3][3];
  for (int l = 0; l < 3; ++l)
    for (int o = 0; o < 3; ++o) {
      Wp[l][o] = (const float*)d_in[3 + l * 6 + o * 2];
      bp[l][o] = (const float*)d_in[3 + l * 6 + o * 2 + 1];
    }

  const size_t F2E = (size_t)NB * NN * NN * OC;  // 33,554,432 elems
  const size_t X2E = (size_t)NB * NN * NN * 64;  // 16,777,216 elems

  uint8_t* ws = (uint8_t*)d_ws;
  size_t off = 0;
  auto carve = [&](size_t bytes) -> uint8_t* {
    uint8_t* p = ws + off;
    off += (bytes + 255) & ~(size_t)255;
    return p;
  };
  float* f0a = (float*)carve((size_t)NB * OC * 4);
  float* f0b = (float*)carve((size_t)NB * OC * 4);
  float* f1a = (float*)carve((size_t)NB * NN * OC * 4);
  float* f1b = (float*)carve((size_t)NB * NN * OC * 4);
  float* r2  = (float*)carve((size_t)NB * NN * 256 * 4);
  float* uu  = (float*)carve((size_t)NB * NN * OC * 4);
  float* vv  = (float*)carve((size_t)NB * NN * OC * 4);
  uint16_t* Wt0 = (uint16_t*)carve((size_t)OC * 128 * 2);
  uint16_t* Wt1 = (uint16_t*)carve((size_t)OC * 256 * 2);
  uint16_t* Wt2 = (uint16_t*)carve((size_t)OC * 256 * 2);
  __hip_bfloat16* f2a = (__hip_bfloat16*)carve(F2E * 2);

  __hip_bfloat16* f2b;
  uint16_t* x2bf;
  if (ws_size >= off + F2E * 2) {
    // plan A: second big buffer in ws; x2bf aliases it (dead before f2b live)
    f2b = (__hip_bfloat16*)carve(F2E * 2);
    x2bf = (uint16_t*)f2b;
  } else {
    // plan B: layer-1 f2 output overwrites x2 (x2 fully consumed in layer 0;
    // harness restores inputs before every launch). x2bf gets its own carve.
    f2b = (__hip_bfloat16*)d_in[2];
    x2bf = (uint16_t*)carve(X2E * 2);
  }

  float* out_f0 = (float*)d_out;
  float* out_f1 = out_f0 + (size_t)NB * OC;
  float* out_f2 = out_f1 + (size_t)NB * NN * OC;

  // weight transposes (bf16 [n][k] for the big GEMM)
  prep_wt_kernel<<<64, 256, 0, stream>>>(Wp[0][2], Wt0, 64, 64);
  prep_wt_kernel<<<128, 256, 0, stream>>>(Wp[1][2], Wt1, 128, 128);
  prep_wt_kernel<<<128, 256, 0, stream>>>(Wp[2][2], Wt2, 128, 128);

  // ---- layer 0 (d0=32, d1=64, d2=64) ----
  reduce2_l0_kernel<<<NB * NN, 256, 0, stream>>>(x2, r2, x2bf);
  o0_kernel<32, 64><<<NB, 256, 0, stream>>>(x0, x1, Wp[0][0], bp[0][0], f0a);
  uv_kernel<64, 64><<<NB * NN, 128, 0, stream>>>(x1, Wp[0][2], bp[0][2], uu, vv);
  o1_kernel<32, 64, 64><<<NB * NN, 128, 0, stream>>>(x0, x1, r2, Wp[0][1],
                                                     bp[0][1], f1a);
  gemm2_kernel<64, __hip_bfloat16><<<NB * NN * 2, 256, 0, stream>>>(
      (const __hip_bfloat16*)x2bf, Wt0, uu, vv, f2a);

  // ---- layer 1 (all dims 128) ----
  reduce2_bf_kernel<<<NB * NN, 256, 0, stream>>>(f2a, r2);
  o0_kernel<128, 128><<<NB, 256, 0, stream>>>(f0a, f1a, Wp[1][0], bp[1][0], f0b);
  uv_kernel<128, 128><<<NB * NN, 128, 0, stream>>>(f1a, Wp[1][2], bp[1][2], uu, vv);
  o1_kernel<128, 128, 128><<<NB * NN, 128, 0, stream>>>(f0a, f1a, r2, Wp[1][1],
                                                        bp[1][1], f1b);
  gemm2_kernel<128, __hip_bfloat16><<<NB * NN * 2, 256, 0, stream>>>(
      f2a, Wt1, uu, vv, f2b);

  // ---- layer 2 (all dims 128; fp32 outputs straight to d_out) ----
  reduce2_bf_kernel<<<NB * NN, 256, 0, stream>>>(f2b, r2);
  o0_kernel<128, 128><<<NB, 256, 0, stream>>>(f0b, f1b, Wp[2][0], bp[2][0], out_f0);
  uv_kernel<128, 128><<<NB * NN, 128, 0, stream>>>(f1b, Wp[2][2], bp[2][2], uu, vv);
  o1_kernel<128, 128, 128><<<NB * NN, 128, 0, stream>>>(f0b, f1b, r2, Wp[2][1],
                                                        bp[2][1], out_f1);
  gemm2_kernel<128, float><<<NB * NN * 2, 256, 0, stream>>>(f2b, Wt2, uu, vv,
                                                            out_f2);
}

// Round 2
// 584.803 us; speedup vs baseline: 1.0820x; 1.0820x over previous
//
#include <hip/hip_runtime.h>
#include <hip/hip_bf16.h>
#include <cstdint>

#define NN 256
#define NB 4
#define OC 128

using bf16x8_t = __attribute__((ext_vector_type(8))) __bf16;
using f32x4_t  = __attribute__((ext_vector_type(4))) float;

typedef const __attribute__((address_space(1))) uint8_t* gptr1_t;
typedef __attribute__((address_space(3))) uint8_t* lptr3_t;

__device__ __forceinline__ void async_load16(const void* g, void* l) {
  __builtin_amdgcn_global_load_lds((gptr1_t)g, (lptr3_t)l, 16, 0, 0);
}

__device__ __forceinline__ float sigf(float x) {
  return 1.0f / (1.0f + __expf(-x));
}

__device__ __forceinline__ uint16_t f2bf_rne(float f) {
  uint32_t u = __float_as_uint(f);
  uint32_t r = (u + 0x7fffu + ((u >> 16) & 1u)) >> 16;
  return (uint16_t)r;
}

// ---------------------------------------------------------------------------
// reduce2 for layer 0: fp32 input [B,n,n,64] -> r2 [B,n,128] fp32, plus bf16
// copy of x2 (GEMM A operand).
// ---------------------------------------------------------------------------
__global__ __launch_bounds__(256) void reduce2_l0_kernel(
    const float* __restrict__ x2, float* __restrict__ r2,
    uint16_t* __restrict__ x2bf) {
  const int bid = blockIdx.x;            // b*256 + i
  const int b = bid >> 8, i = bid & 255;
  const int tid = threadIdx.x;
  const int q = tid & 15, s = tid >> 4;  // 16 quads, 16 stripes
  const size_t rowbase = ((size_t)(b * NN + i) * NN) * 64 + q * 4;
  float mx0 = 0.f, mx1 = 0.f, mx2 = 0.f, mx3 = 0.f;
  float mn0 = 1.f, mn1 = 1.f, mn2 = 1.f, mn3 = 1.f;
  for (int j = s; j < NN; j += 16) {
    const float4 x = *(const float4*)(x2 + rowbase + (size_t)j * 64);
    uint2 pk;
    pk.x = (uint32_t)f2bf_rne(x.x) | ((uint32_t)f2bf_rne(x.y) << 16);
    pk.y = (uint32_t)f2bf_rne(x.z) | ((uint32_t)f2bf_rne(x.w) << 16);
    *(uint2*)(x2bf + rowbase + (size_t)j * 64) = pk;
    if (j != i) {
      mx0 = fmaxf(mx0, x.x); mx1 = fmaxf(mx1, x.y);
      mx2 = fmaxf(mx2, x.z); mx3 = fmaxf(mx3, x.w);
      mn0 = fminf(mn0, x.x); mn1 = fminf(mn1, x.y);
      mn2 = fminf(mn2, x.z); mn3 = fminf(mn3, x.w);
    }
  }
  __shared__ float4 smx[256], smn[256];
  smx[tid] = make_float4(mx0, mx1, mx2, mx3);
  smn[tid] = make_float4(mn0, mn1, mn2, mn3);
  __syncthreads();
  if (s == 0) {
    for (int ss = 1; ss < 16; ++ss) {
      float4 a = smx[q + ss * 16], c = smn[q + ss * 16];
      mx0 = fmaxf(mx0, a.x); mx1 = fmaxf(mx1, a.y);
      mx2 = fmaxf(mx2, a.z); mx3 = fmaxf(mx3, a.w);
      mn0 = fminf(mn0, c.x); mn1 = fminf(mn1, c.y);
      mn2 = fminf(mn2, c.z); mn3 = fminf(mn3, c.w);
    }
    float* r = r2 + (size_t)(b * NN + i) * 128;
    r[q * 4 + 0] = mx0; r[q * 4 + 1] = mx1; r[q * 4 + 2] = mx2; r[q * 4 + 3] = mx3;
    r[64 + q * 4 + 0] = mn0; r[64 + q * 4 + 1] = mn1;
    r[64 + q * 4 + 2] = mn2; r[64 + q * 4 + 3] = mn3;
  }
}

// ---------------------------------------------------------------------------
// prep: build bf16 Wt[n][k] for all three layers in one launch.
// k<d2 -> W2[d1+k][n] (Wb), else W2[2*d1+d2+(k-d2)][n] (Wd).
// ---------------------------------------------------------------------------
__device__ __forceinline__ void emit_wt(const float* __restrict__ W2,
                                        uint16_t* __restrict__ Wt, int d1,
                                        int d2, int idx) {
  const int K = 2 * d2;
  const int nn = idx / K, k = idx - nn * K;
  const int row = (k < d2) ? (d1 + k) : (2 * d1 + d2 + (k - d2));
  Wt[idx] = f2bf_rne(W2[row * OC + nn]);
}

__global__ void prep_wt_all(const float* __restrict__ W20,
                            const float* __restrict__ W21,
                            const float* __restrict__ W22,
                            uint16_t* __restrict__ Wt0,
                            uint16_t* __restrict__ Wt1,
                            uint16_t* __restrict__ Wt2) {
  const int g = blockIdx.x * 256 + threadIdx.x;
  if (g < 16384) emit_wt(W20, Wt0, 64, 64, g);
  else if (g < 16384 + 32768) emit_wt(W21, Wt1, 128, 128, g - 16384);
  else emit_wt(W22, Wt2, 128, 128, g - 49152);
}

// ---------------------------------------------------------------------------
// Fused small kernel (per layer): o1 + u/v for 4 (b,i) rows per block, plus
// o0 (in the 4 blocks with i0==0) and init of next layer's r2.
//   g1 = [f0, f1[b,i], r2[b,i]];  o1 = sigmoid(g1 @ W1 + b1)
//   u  = f1 @ Wa + b2 ; v = f1 @ Wc   (Wa=W2 rows [0,d1), Wc=[d1+d2,d1+d2+d1))
//   o0 = sigmoid([f0, max_i f1, min_i f1] @ W0 + b0)
// 256 threads: c = tid&127 (col), s = tid>>7 (k-half). ROWS=4 amortizes the
// W1/W2 L2 reads 4x.
// ---------------------------------------------------------------------------
template <int D0, int D1, int D2, bool HAS_NEXT>
__global__ __launch_bounds__(256) void small_kernel(
    const float* __restrict__ f0in, const float* __restrict__ f1in,
    const float* __restrict__ r2in, const float* __restrict__ W0,
    const float* __restrict__ b0, const float* __restrict__ W1,
    const float* __restrict__ b1, const float* __restrict__ W2,
    const float* __restrict__ b2, float* __restrict__ f0out,
    float* __restrict__ f1out, float* __restrict__ u, float* __restrict__ v,
    float* __restrict__ r2n) {
  constexpr int FIN1 = D0 + D1 + 2 * D2;
  constexpr int FIN0 = D0 + 2 * D1;
  constexpr int ROWS = 4;
  const int blk = blockIdx.x;            // NB*NN/ROWS = 256 blocks
  const int bi0 = blk * ROWS;
  const int b = bi0 >> 8;
  const int tid = threadIdx.x;
  const int c = tid & 127, s = tid >> 7;

  __shared__ float g1[ROWS][FIN1];
  __shared__ float part[3][ROWS][2][128];
  __shared__ float g0[FIN0];
  __shared__ float rmx[256], rmn[256];

  // stage g1 rows
  for (int r = 0; r < ROWS; ++r) {
    const int bi = bi0 + r;
    for (int k = tid; k < FIN1; k += 256) {
      float x;
      if (k < D0) x = f0in[b * D0 + k];
      else if (k < D0 + D1) x = f1in[(size_t)bi * D1 + (k - D0)];
      else x = r2in[(size_t)bi * (2 * D2) + (k - D0 - D1)];
      g1[r][k] = x;
    }
  }
  __syncthreads();

  // o1 partial dot over k-half s
  float a1[ROWS] = {0.f, 0.f, 0.f, 0.f};
  constexpr int H1 = FIN1 / 2;
#pragma unroll 4
  for (int k = s * H1; k < s * H1 + H1; ++k) {
    const float w = W1[(size_t)k * OC + c];
#pragma unroll
    for (int r = 0; r < ROWS; ++r) a1[r] += g1[r][k] * w;
  }
  // u/v partial dots over D1-half
  float au[ROWS] = {0.f, 0.f, 0.f, 0.f};
  float av[ROWS] = {0.f, 0.f, 0.f, 0.f};
  constexpr int H2 = D1 / 2;
#pragma unroll 4
  for (int k = s * H2; k < s * H2 + H2; ++k) {
    const float wu = W2[(size_t)k * OC + c];
    const float wv = W2[(size_t)(D1 + D2 + k) * OC + c];
#pragma unroll
    for (int r = 0; r < ROWS; ++r) {
      const float x = g1[r][D0 + k];
      au[r] += x * wu;
      av[r] += x * wv;
    }
  }
#pragma unroll
  for (int r = 0; r < ROWS; ++r) {
    part[0][r][s][c] = a1[r];
    part[1][r][s][c] = au[r];
    part[2][r][s][c] = av[r];
  }
  __syncthreads();
  if (s == 0) {
#pragma unroll
    for (int r = 0; r < ROWS; ++r) {
      const size_t bi = bi0 + r;
      f1out[bi * OC + c] = sigf(a1[r] + part[0][r][1][c] + b1[c]);
      u[bi * OC + c] = au[r] + part[1][r][1][c] + b2[c];
      v[bi * OC + c] = av[r] + part[2][r][1][c];
    }
  }
  if (HAS_NEXT) {
    // init next-layer r2: max part = 0, min part = 1
#pragma unroll
    for (int r = 0; r < ROWS; ++r)
      r2n[(size_t)(bi0 + r) * 256 + s * 128 + c] = (s == 0) ? 0.f : 1.f;
  }

  // o0 in one block per batch (block-uniform branch; barriers inside are legal)
  if ((blk & 63) == 0) {
    constexpr int S = 256 / D1;
    const int cc = tid & (D1 - 1), ss = tid / D1;
    float mx = -1e30f, mn = 1e30f;
    for (int j = ss; j < NN; j += S) {
      const float x = f1in[((size_t)b * NN + j) * D1 + cc];
      mx = fmaxf(mx, x); mn = fminf(mn, x);
    }
    rmx[tid] = mx; rmn[tid] = mn;
    __syncthreads();
    if (ss == 0) {
      for (int s2 = 1; s2 < S; ++s2) {
        mx = fmaxf(mx, rmx[cc + s2 * D1]);
        mn = fminf(mn, rmn[cc + s2 * D1]);
      }
      g0[D0 + cc] = mx;
      g0[D0 + D1 + cc] = mn;
    }
    if (tid < D0) g0[tid] = f0in[b * D0 + tid];
    __syncthreads();
    if (tid < OC) {
      float acc = b0[tid];
#pragma unroll 8
      for (int k = 0; k < FIN0; ++k) acc += g0[k] * W0[k * OC + tid];
      f0out[b * OC + tid] = sigf(acc);
    }
  }
}

// ---------------------------------------------------------------------------
// Big order-2 GEMM. Block = (b, i, j-tile of 128): output 128 rows x 128 ch.
//   acc[j,c] = sum_k f2[b,i,j,k]*Wb[k,c] + sum_k f2[b,j,i,k]*Wd[k,c]
//   out = sigmoid(acc + u[b,i,c] + v[b,j,c])
// bf16 output path stages the tile in LDS (272B-padded rows) for coalesced
// dwordx4 stores, and fuses next-layer reduce2 (max/min over j, excluding
// j==i) via LDS + device atomics on uint (valid: all values in (0,1)).
// ---------------------------------------------------------------------------
template <int D2, typename OUT_T, bool REDUCE>
__global__ __launch_bounds__(256, 3) void gemm2_kernel(
    const __hip_bfloat16* __restrict__ f2, const uint16_t* __restrict__ Wt,
    const float* __restrict__ u, const float* __restrict__ v,
    OUT_T* __restrict__ out, float* __restrict__ r2n) {
  constexpr int K = 2 * D2;
  constexpr int NCH = K / 64;
  constexpr bool BF16OUT = (sizeof(OUT_T) == 2);
  constexpr int LDSB = BF16OUT ? (128 * 272) : 32768;  // stage tile needs 34816
  const int bid = blockIdx.x;
  const int jt = bid & 1, i = (bid >> 1) & 255, b = bid >> 9;
  const int j0 = jt * 128;
  const int tid = threadIdx.x;
  const int wv = tid >> 6, lane = tid & 63;
  const int wr = wv >> 1, wc = wv & 1;
  const int l15 = lane & 15, l4 = lane >> 4;

  __shared__ __align__(16) uint8_t lds[LDSB];
  __shared__ unsigned smax[128], smin[128];
  uint8_t* const ldsA = lds;
  uint8_t* const ldsW = lds + 16384;

  const __hip_bfloat16* A1 = f2 + ((size_t)(b * NN + i) * NN + j0) * D2;
  const __hip_bfloat16* A2 = f2 + ((size_t)(b * NN + j0) * NN + i) * D2;

  f32x4_t acc[4][4];
#pragma unroll
  for (int a = 0; a < 4; ++a)
#pragma unroll
    for (int q = 0; q < 4; ++q) acc[a][q] = (f32x4_t){0.f, 0.f, 0.f, 0.f};

  for (int c = 0; c < NCH; ++c) {
    const int kbg = c * 64;
    const bool second = (kbg >= D2);
    const __hip_bfloat16* Ab = second ? A2 : A1;
    const size_t rstride = second ? (size_t)NN * D2 : (size_t)D2;
    const int kbase = second ? (kbg - D2) : kbg;
#pragma unroll
    for (int q = 0; q < 4; ++q) {  // A units: id = (ks*8 + mi)
      const int id = wv * 4 + q;
      const int mi = id & 7, ks = id >> 3;
      const int row = mi * 16 + l15;
      const int kk = ks * 32 + l4 * 8;
      async_load16(Ab + (size_t)row * rstride + kbase + kk, ldsA + id * 1024);
    }
#pragma unroll
    for (int q = 0; q < 4; ++q) {  // W units: id = (ks*8 + ni)
      const int id = wv * 4 + q;
      const int ni = id & 7, ks = id >> 3;
      const int nn2 = ni * 16 + l15;
      const int kk = ks * 32 + l4 * 8;
      async_load16(Wt + (size_t)nn2 * K + kbg + kk, ldsW + id * 1024);
    }
    __syncthreads();
#pragma unroll
    for (int ks = 0; ks < 2; ++ks) {
      bf16x8_t Af[4], Bf[4];
#pragma unroll
      for (int a = 0; a < 4; ++a)
        Af[a] = *(const bf16x8_t*)(ldsA + ((ks * 8 + wr * 4 + a) << 10) + (lane << 4));
#pragma unroll
      for (int q = 0; q < 4; ++q)
        Bf[q] = *(const bf16x8_t*)(ldsW + ((ks * 8 + wc * 4 + q) << 10) + (lane << 4));
#pragma unroll
      for (int a = 0; a < 4; ++a)
#pragma unroll
        for (int q = 0; q < 4; ++q)
          acc[a][q] = __builtin_amdgcn_mfma_f32_16x16x32_bf16(Af[a], Bf[q],
                                                              acc[a][q], 0, 0, 0);
    }
    __syncthreads();
  }

  // epilogue: C/D layout col = lane&15, row = (lane>>4)*4 + reg
  const size_t bi2 = (size_t)(b * NN + i);
  float uval[4];
#pragma unroll
  for (int q = 0; q < 4; ++q) uval[q] = u[bi2 * OC + wc * 64 + q * 16 + l15];
  const size_t obase = (bi2 * NN + j0) * OC;
  const size_t vbase = (size_t)(b * NN + j0) * OC;

  if (BF16OUT) {
    if (REDUCE && tid < 128) { smax[tid] = 0u; smin[tid] = 0x3f800000u; }
    __syncthreads();
    float lmx[4] = {0.f, 0.f, 0.f, 0.f};
    float lmn[4] = {1.f, 1.f, 1.f, 1.f};
#pragma unroll
    for (int a = 0; a < 4; ++a) {
      const int rowb = wr * 64 + a * 16 + l4 * 4;
#pragma unroll
      for (int r = 0; r < 4; ++r) {
        const int j = rowb + r;
        const bool excl = (j0 + j) == i;
#pragma unroll
        for (int q = 0; q < 4; ++q) {
          const int col = wc * 64 + q * 16 + l15;
          const float x = acc[a][q][r] + uval[q] + v[vbase + (size_t)j * OC + col];
          const float sg = sigf(x);
          *(uint16_t*)(lds + j * 272 + col * 2) = f2bf_rne(sg);
          if (REDUCE && !excl) {
            lmx[q] = fmaxf(lmx[q], sg);
            lmn[q] = fminf(lmn[q], sg);
          }
        }
      }
    }
    if (REDUCE) {
#pragma unroll
      for (int q = 0; q < 4; ++q) {
        const int col = wc * 64 + q * 16 + l15;
        atomicMax(&smax[col], __float_as_uint(lmx[q]));
        atomicMin(&smin[col], __float_as_uint(lmn[q]));
      }
    }
    __syncthreads();
    // coalesced stores: 2048 16B-chunks, 8 per thread
    uint16_t* const outp = (uint16_t*)out;
#pragma unroll
    for (int ci = 0; ci < 8; ++ci) {
      const int chunk = ci * 256 + tid;
      const int row = chunk >> 4, off = chunk & 15;
      const uint4 val = *(const uint4*)(lds + row * 272 + off * 16);
      *(uint4*)(outp + obase + (size_t)row * OC + off * 8) = val;
    }
    if (REDUCE && tid < 128) {
      unsigned* const r2u = (unsigned*)r2n;
      atomicMax(&r2u[bi2 * 256 + tid], smax[tid]);
      atomicMin(&r2u[bi2 * 256 + 128 + tid], smin[tid]);
    }
  } else {
    // fp32 direct stores (64B segments per 16 lanes — already coalesced)
    float* const outp = (float*)out;
#pragma unroll
    for (int a = 0; a < 4; ++a) {
      const int rowb = wr * 64 + a * 16 + l4 * 4;
#pragma unroll
      for (int r = 0; r < 4; ++r) {
        const int j = rowb + r;
#pragma unroll
        for (int q = 0; q < 4; ++q) {
          const int col = wc * 64 + q * 16 + l15;
          const float x = acc[a][q][r] + uval[q] + v[vbase + (size_t)j * OC + col];
          outp[obase + (size_t)j * OC + col] = sigf(x);
        }
      }
    }
  }
}

// ---------------------------------------------------------------------------
extern "C" void kernel_launch(void* const* d_in, const int* in_sizes, int n_in,
                              void* d_out, int out_size, void* d_ws,
                              size_t ws_size, hipStream_t stream) {
  const float* x0 = (const float*)d_in[0];
  const float* x1 = (const float*)d_in[1];
  const float* x2 = (const float*)d_in[2];
  const float *Wp[3][3], *bp[3][3];
  for (int l = 0; l < 3; ++l)
    for (int o = 0; o < 3; ++o) {
      Wp[l][o] = (const float*)d_in[3 + l * 6 + o * 2];
      bp[l][o] = (const float*)d_in[3 + l * 6 + o * 2 + 1];
    }

  const size_t F2E = (size_t)NB * NN * NN * OC;  // 33,554,432 elems
  const size_t X2E = (size_t)NB * NN * NN * 64;

  uint8_t* ws = (uint8_t*)d_ws;
  size_t off = 0;
  auto carve = [&](size_t bytes) -> uint8_t* {
    uint8_t* p = ws + off;
    off += (bytes + 255) & ~(size_t)255;
    return p;
  };
  float* f0a = (float*)carve((size_t)NB * OC * 4);
  float* f0b = (float*)carve((size_t)NB * OC * 4);
  float* f1a = (float*)carve((size_t)NB * NN * OC * 4);
  float* f1b = (float*)carve((size_t)NB * NN * OC * 4);
  float* r2a = (float*)carve((size_t)NB * NN * 128 * 4);
  float* r2b = (float*)carve((size_t)NB * NN * 256 * 4);
  float* r2c = (float*)carve((size_t)NB * NN * 256 * 4);
  float* uu  = (float*)carve((size_t)NB * NN * OC * 4);
  float* vv  = (float*)carve((size_t)NB * NN * OC * 4);
  uint16_t* Wt0 = (uint16_t*)carve((size_t)OC * 128 * 2);
  uint16_t* Wt1 = (uint16_t*)carve((size_t)OC * 256 * 2);
  uint16_t* Wt2 = (uint16_t*)carve((size_t)OC * 256 * 2);
  __hip_bfloat16* f2a = (__hip_bfloat16*)carve(F2E * 2);

  __hip_bfloat16* f2b;
  uint16_t* x2bf;
  if (ws_size >= off + F2E * 2) {
    // plan A: second big buffer in ws; x2bf aliases it (dead before f2b live)
    f2b = (__hip_bfloat16*)carve(F2E * 2);
    x2bf = (uint16_t*)f2b;
  } else {
    // plan B: layer-1 f2 output overwrites x2 (fully consumed in layer 0)
    f2b = (__hip_bfloat16*)d_in[2];
    x2bf = (uint16_t*)carve(X2E * 2);
  }

  float* out_f0 = (float*)d_out;
  float* out_f1 = out_f0 + (size_t)NB * OC;
  float* out_f2 = out_f1 + (size_t)NB * NN * OC;

  prep_wt_all<<<320, 256, 0, stream>>>(Wp[0][2], Wp[1][2], Wp[2][2], Wt0, Wt1,
                                       Wt2);
  reduce2_l0_kernel<<<NB * NN, 256, 0, stream>>>(x2, r2a, x2bf);

  // ---- layer 0 (d0=32, d1=64, d2=64) ----
  small_kernel<32, 64, 64, true><<<NB * NN / 4, 256, 0, stream>>>(
      x0, x1, r2a, Wp[0][0], bp[0][0], Wp[0][1], bp[0][1], Wp[0][2], bp[0][2],
      f0a, f1a, uu, vv, r2b);
  gemm2_kernel<64, __hip_bfloat16, true><<<NB * NN * 2, 256, 0, stream>>>(
      (const __hip_bfloat16*)x2bf, Wt0, uu, vv, f2a, r2b);

  // ---- layer 1 (all dims 128) ----
  small_kernel<128, 128, 128, true><<<NB * NN / 4, 256, 0, stream>>>(
      f0a, f1a, r2b, Wp[1][0], bp[1][0], Wp[1][1], bp[1][1], Wp[1][2], bp[1][2],
      f0b, f1b, uu, vv, r2c);
  gemm2_kernel<128, __hip_bfloat16, true><<<NB * NN * 2, 256, 0, stream>>>(
      f2a, Wt1, uu, vv, f2b, r2c);

  // ---- layer 2 (outputs straight to d_out) ----
  small_kernel<128, 128, 128, false><<<NB * NN / 4, 256, 0, stream>>>(
      f0b, f1b, r2c, Wp[2][0], bp[2][0], Wp[2][1], bp[2][1], Wp[2][2], bp[2][2],
      out_f0, out_f1, uu, vv, nullptr);
  gemm2_kernel<128, float, false><<<NB * NN * 2, 256, 0, stream>>>(
      f2b, Wt2, uu, vv, out_f2, nullptr);
}

// Round 3
// 539.682 us; speedup vs baseline: 1.1724x; 1.0836x over previous
//
#include <hip/hip_runtime.h>
#include <hip/hip_bf16.h>
#include <cstdint>

#define NN 256
#define NB 4
#define OC 128

using bf16x8_t = __attribute__((ext_vector_type(8))) __bf16;
using f32x4_t  = __attribute__((ext_vector_type(4))) float;

typedef const __attribute__((address_space(1))) uint8_t* gptr1_t;
typedef __attribute__((address_space(3))) uint8_t* lptr3_t;

__device__ __forceinline__ void async_load16(const void* g, void* l) {
  __builtin_amdgcn_global_load_lds((gptr1_t)g, (lptr3_t)l, 16, 0, 0);
}

__device__ __forceinline__ float sigf(float x) {
  return 1.0f / (1.0f + __expf(-x));
}

__device__ __forceinline__ uint16_t f2bf_rne(float f) {
  uint32_t u = __float_as_uint(f);
  uint32_t r = (u + 0x7fffu + ((u >> 16) & 1u)) >> 16;
  return (uint16_t)r;
}

// ---------------------------------------------------------------------------
// prep: bf16 Wt[n][k] (gemm2 B) and Bt[n][k] (small-GEMM B = [W1|Wa|Wc]) for
// all three layers in one launch.
// ---------------------------------------------------------------------------
__device__ __forceinline__ void emit_wt(const float* __restrict__ W2,
                                        uint16_t* __restrict__ Wt, int d1,
                                        int d2, int idx) {
  const int K = 2 * d2;
  const int nn = idx / K, k = idx - nn * K;
  const int row = (k < d2) ? (d1 + k) : (2 * d1 + d2 + (k - d2));
  Wt[idx] = f2bf_rne(W2[row * OC + nn]);
}

__device__ __forceinline__ void emit_bt(const float* __restrict__ W1,
                                        const float* __restrict__ W2,
                                        uint16_t* __restrict__ Bt, int D0,
                                        int D1, int D2, int FIN1, int KP,
                                        int idx) {
  const int n = idx / KP, k = idx - n * KP;
  float val = 0.f;
  if (n < 128) {
    if (k < FIN1) val = W1[k * OC + n];
  } else if (n < 256) {
    if (k >= D0 && k < D0 + D1) val = W2[(k - D0) * OC + (n - 128)];
  } else {
    if (k >= D0 && k < D0 + D1) val = W2[(D1 + D2 + (k - D0)) * OC + (n - 256)];
  }
  Bt[idx] = f2bf_rne(val);
}

__global__ __launch_bounds__(256) void prep_all(
    const float* __restrict__ W2_0, const float* __restrict__ W2_1,
    const float* __restrict__ W2_2, const float* __restrict__ W1_0,
    const float* __restrict__ W1_1, const float* __restrict__ W1_2,
    uint16_t* __restrict__ Wt0, uint16_t* __restrict__ Wt1,
    uint16_t* __restrict__ Wt2, uint16_t* __restrict__ Bt0,
    uint16_t* __restrict__ Bt1, uint16_t* __restrict__ Bt2) {
  int g = blockIdx.x * 256 + threadIdx.x;
  if (g < 16384) { emit_wt(W2_0, Wt0, 64, 64, g); return; }
  g -= 16384;
  if (g < 32768) { emit_wt(W2_1, Wt1, 128, 128, g); return; }
  g -= 32768;
  if (g < 32768) { emit_wt(W2_2, Wt2, 128, 128, g); return; }
  g -= 32768;
  if (g < 98304) { emit_bt(W1_0, W2_0, Bt0, 32, 64, 64, 224, 256, g); return; }
  g -= 98304;
  if (g < 196608) { emit_bt(W1_1, W2_1, Bt1, 128, 128, 128, 512, 512, g); return; }
  g -= 196608;
  if (g < 196608) { emit_bt(W1_2, W2_2, Bt2, 128, 128, 128, 512, 512, g); }
}

// ---------------------------------------------------------------------------
// reduce2 layer 0: fp32 x2 [B,n,n,64] -> bf16 x2bf (gemm2 A) + g1bf0 rows
// [f0(32) | f1(64) | max(64) | min(64) | pad(32)] bf16, + init r2b (0/1).
// ---------------------------------------------------------------------------
__global__ __launch_bounds__(256) void reduce2_l0_kernel(
    const float* __restrict__ x2, const float* __restrict__ x0,
    const float* __restrict__ x1, uint16_t* __restrict__ g1bf0,
    uint16_t* __restrict__ x2bf, float* __restrict__ r2init) {
  const int bid = blockIdx.x;            // b*256 + i
  const int b = bid >> 8, i = bid & 255;
  const int tid = threadIdx.x;
  const int q = tid & 15, s = tid >> 4;  // 16 quads, 16 stripes
  const size_t rowbase = ((size_t)bid * NN) * 64 + q * 4;
  float mx0 = 0.f, mx1 = 0.f, mx2 = 0.f, mx3 = 0.f;
  float mn0 = 1.f, mn1 = 1.f, mn2 = 1.f, mn3 = 1.f;
  for (int j = s; j < NN; j += 16) {
    const float4 x = *(const float4*)(x2 + rowbase + (size_t)j * 64);
    uint2 pk;
    pk.x = (uint32_t)f2bf_rne(x.x) | ((uint32_t)f2bf_rne(x.y) << 16);
    pk.y = (uint32_t)f2bf_rne(x.z) | ((uint32_t)f2bf_rne(x.w) << 16);
    *(uint2*)(x2bf + rowbase + (size_t)j * 64) = pk;
    if (j != i) {
      mx0 = fmaxf(mx0, x.x); mx1 = fmaxf(mx1, x.y);
      mx2 = fmaxf(mx2, x.z); mx3 = fmaxf(mx3, x.w);
      mn0 = fminf(mn0, x.x); mn1 = fminf(mn1, x.y);
      mn2 = fminf(mn2, x.z); mn3 = fminf(mn3, x.w);
    }
  }
  __shared__ float4 smx[256], smn[256];
  smx[tid] = make_float4(mx0, mx1, mx2, mx3);
  smn[tid] = make_float4(mn0, mn1, mn2, mn3);
  __syncthreads();
  uint16_t* const g = g1bf0 + (size_t)bid * 256;
  if (s == 0) {
    for (int ss = 1; ss < 16; ++ss) {
      float4 a = smx[q + ss * 16], c = smn[q + ss * 16];
      mx0 = fmaxf(mx0, a.x); mx1 = fmaxf(mx1, a.y);
      mx2 = fmaxf(mx2, a.z); mx3 = fmaxf(mx3, a.w);
      mn0 = fminf(mn0, c.x); mn1 = fminf(mn1, c.y);
      mn2 = fminf(mn2, c.z); mn3 = fminf(mn3, c.w);
    }
    g[96 + q * 4 + 0] = f2bf_rne(mx0); g[96 + q * 4 + 1] = f2bf_rne(mx1);
    g[96 + q * 4 + 2] = f2bf_rne(mx2); g[96 + q * 4 + 3] = f2bf_rne(mx3);
    g[160 + q * 4 + 0] = f2bf_rne(mn0); g[160 + q * 4 + 1] = f2bf_rne(mn1);
    g[160 + q * 4 + 2] = f2bf_rne(mn2); g[160 + q * 4 + 3] = f2bf_rne(mn3);
  }
  if (tid < 32) g[tid] = f2bf_rne(x0[b * 32 + tid]);
  else if (tid < 96) g[tid] = f2bf_rne(x1[(size_t)bid * 64 + tid - 32]);
  else if (tid >= 224) g[tid] = 0;
  r2init[(size_t)bid * 256 + tid] = (tid < 128) ? 0.f : 1.f;
}

// ---------------------------------------------------------------------------
// o0 (tiny, one block per batch): f0out = sigmoid([f0, max f1, min f1]@W0+b0);
// optional bf16 broadcast into next layer's g1 rows (f0 slot, width 512).
// ---------------------------------------------------------------------------
template <int D0, int D1, bool DUP>
__global__ __launch_bounds__(256) void o0_kernel(
    const float* __restrict__ f0, const float* __restrict__ f1,
    const float* __restrict__ W0, const float* __restrict__ b0,
    float* __restrict__ f0out, uint16_t* __restrict__ g1next) {
  constexpr int FIN = D0 + 2 * D1;
  constexpr int S = 256 / D1;
  const int b = blockIdx.x;
  const int tid = threadIdx.x;
  const int c = tid & (D1 - 1), s = tid / D1;
  __shared__ float g0[FIN];
  __shared__ float smx[256], smn[256];
  __shared__ float sval[128];
  float mx = -1e30f, mn = 1e30f;
  const float* f1b = f1 + (size_t)b * NN * D1;
  for (int j = s; j < NN; j += S) {
    float x = f1b[(size_t)j * D1 + c];
    mx = fmaxf(mx, x); mn = fminf(mn, x);
  }
  smx[tid] = mx; smn[tid] = mn;
  __syncthreads();
  if (s == 0) {
    for (int ss = 1; ss < S; ++ss) {
      mx = fmaxf(mx, smx[c + ss * D1]);
      mn = fminf(mn, smn[c + ss * D1]);
    }
    g0[D0 + c] = mx;
    g0[D0 + D1 + c] = mn;
  }
  if (tid < D0) g0[tid] = f0[b * D0 + tid];
  __syncthreads();
  if (tid < OC) {
    float acc = b0[tid];
#pragma unroll 8
    for (int k = 0; k < FIN; ++k) acc += g0[k] * W0[k * OC + tid];
    const float val = sigf(acc);
    f0out[b * OC + tid] = val;
    sval[tid] = val;
  }
  if (DUP) {
    __syncthreads();
    for (int idx = tid; idx < 256 * 128; idx += 256) {
      const int row = idx >> 7, cc = idx & 127;
      g1next[((size_t)(b * 256 + row)) * 512 + cc] = f2bf_rne(sval[cc]);
    }
  }
}

// ---------------------------------------------------------------------------
// Small fused MFMA GEMM: C[1024 x 384] = g1[1024 x KP](bf16) @ Bt^T, where
// Bt = [W1 | Wa(pad) | Wc(pad)] (384 x KP bf16).
//   nt=0 cols: f1out = sigmoid(acc + b1)   (+ optional bf16 dup into g1next)
//   nt=1 cols: u = acc + b2
//   nt=2 cols: v = acc
// Block = 64 rows x 128 cols; 4 waves each 64x32 (4x2 frags). Grid 48.
// ---------------------------------------------------------------------------
template <int KP, bool DUP>
__global__ __launch_bounds__(256) void small_gemm(
    const uint16_t* __restrict__ g1, const uint16_t* __restrict__ Bt,
    const float* __restrict__ b1, const float* __restrict__ b2,
    float* __restrict__ f1out, uint16_t* __restrict__ g1next,
    float* __restrict__ u, float* __restrict__ v) {
  constexpr int NCH = KP / 64;
  const int bid = blockIdx.x;
  const int mt = bid / 3, nt = bid - mt * 3;
  const int m0 = mt * 64, n0 = nt * 128;
  const int tid = threadIdx.x;
  const int wv = tid >> 6, lane = tid & 63;
  const int l15 = lane & 15, l4 = lane >> 4;

  __shared__ __align__(16) uint8_t ldsA[8192];
  __shared__ __align__(16) uint8_t ldsB[16384];

  f32x4_t acc[4][2];
#pragma unroll
  for (int a = 0; a < 4; ++a)
#pragma unroll
    for (int q = 0; q < 2; ++q) acc[a][q] = (f32x4_t){0.f, 0.f, 0.f, 0.f};

  for (int c = 0; c < NCH; ++c) {
    const int kbg = c * 64;
#pragma unroll
    for (int t = 0; t < 2; ++t) {  // A units: id = ks*4 + mi (16r x 32k each)
      const int id = wv * 2 + t;
      const int mi = id & 3, ks = id >> 2;
      async_load16(g1 + (size_t)(m0 + mi * 16 + l15) * KP + kbg + ks * 32 + l4 * 8,
                   ldsA + id * 1024);
    }
#pragma unroll
    for (int t = 0; t < 4; ++t) {  // B units: id = ks*8 + ni
      const int id = wv * 4 + t;
      const int ni = id & 7, ks = id >> 3;
      async_load16(Bt + (size_t)(n0 + ni * 16 + l15) * KP + kbg + ks * 32 + l4 * 8,
                   ldsB + id * 1024);
    }
    __syncthreads();
#pragma unroll
    for (int ks = 0; ks < 2; ++ks) {
      bf16x8_t Af[4], Bf[2];
#pragma unroll
      for (int a = 0; a < 4; ++a)
        Af[a] = *(const bf16x8_t*)(ldsA + ((ks * 4 + a) << 10) + (lane << 4));
#pragma unroll
      for (int q = 0; q < 2; ++q)
        Bf[q] = *(const bf16x8_t*)(ldsB + ((ks * 8 + wv * 2 + q) << 10) + (lane << 4));
#pragma unroll
      for (int a = 0; a < 4; ++a)
#pragma unroll
        for (int q = 0; q < 2; ++q)
          acc[a][q] = __builtin_amdgcn_mfma_f32_16x16x32_bf16(Af[a], Bf[q],
                                                              acc[a][q], 0, 0, 0);
    }
    __syncthreads();
  }

  // epilogue; C/D: col = lane&15, row = l4*4 + reg (within 16x16)
  float bias[2];
#pragma unroll
  for (int q = 0; q < 2; ++q) {
    const int cc = wv * 32 + q * 16 + l15;
    bias[q] = (nt == 0) ? b1[cc] : ((nt == 1) ? b2[cc] : 0.f);
  }
#pragma unroll
  for (int a = 0; a < 4; ++a) {
    const int rl = a * 16 + l4 * 4;
#pragma unroll
    for (int r = 0; r < 4; ++r) {
      const size_t bi = m0 + rl + r;
#pragma unroll
      for (int q = 0; q < 2; ++q) {
        const int cc = wv * 32 + q * 16 + l15;
        const float x = acc[a][q][r] + bias[q];
        if (nt == 0) {
          const float val = sigf(x);
          f1out[bi * OC + cc] = val;
          if (DUP) g1next[bi * 512 + 128 + cc] = f2bf_rne(val);
        } else if (nt == 1) {
          u[bi * OC + cc] = x;
        } else {
          v[bi * OC + cc] = x;
        }
      }
    }
  }
}

// ---------------------------------------------------------------------------
// conv: fp32 r2 (post gemm2 atomics) -> bf16 into g1next r2 slot [256..512);
// optionally init the following layer's r2 accumulator (max=0, min=1).
// ---------------------------------------------------------------------------
template <bool INIT_NEXT>
__global__ __launch_bounds__(256) void conv_r2_kernel(
    const float* __restrict__ r2, uint16_t* __restrict__ g1next,
    float* __restrict__ r2next) {
  const int bi = blockIdx.x, t = threadIdx.x;
  g1next[(size_t)bi * 512 + 256 + t] = f2bf_rne(r2[(size_t)bi * 256 + t]);
  if (INIT_NEXT) r2next[(size_t)bi * 256 + t] = (t < 128) ? 0.f : 1.f;
}

// ---------------------------------------------------------------------------
// Big order-2 GEMM (unchanged from round 2).
// ---------------------------------------------------------------------------
template <int D2, typename OUT_T, bool REDUCE>
__global__ __launch_bounds__(256, 3) void gemm2_kernel(
    const __hip_bfloat16* __restrict__ f2, const uint16_t* __restrict__ Wt,
    const float* __restrict__ u, const float* __restrict__ v,
    OUT_T* __restrict__ out, float* __restrict__ r2n) {
  constexpr int K = 2 * D2;
  constexpr int NCH = K / 64;
  constexpr bool BF16OUT = (sizeof(OUT_T) == 2);
  constexpr int LDSB = BF16OUT ? (128 * 272) : 32768;
  const int bid = blockIdx.x;
  const int jt = bid & 1, i = (bid >> 1) & 255, b = bid >> 9;
  const int j0 = jt * 128;
  const int tid = threadIdx.x;
  const int wv = tid >> 6, lane = tid & 63;
  const int wr = wv >> 1, wc = wv & 1;
  const int l15 = lane & 15, l4 = lane >> 4;

  __shared__ __align__(16) uint8_t lds[LDSB];
  __shared__ unsigned smax[128], smin[128];
  uint8_t* const ldsA = lds;
  uint8_t* const ldsW = lds + 16384;

  const __hip_bfloat16* A1 = f2 + ((size_t)(b * NN + i) * NN + j0) * D2;
  const __hip_bfloat16* A2 = f2 + ((size_t)(b * NN + j0) * NN + i) * D2;

  f32x4_t acc[4][4];
#pragma unroll
  for (int a = 0; a < 4; ++a)
#pragma unroll
    for (int q = 0; q < 4; ++q) acc[a][q] = (f32x4_t){0.f, 0.f, 0.f, 0.f};

  for (int c = 0; c < NCH; ++c) {
    const int kbg = c * 64;
    const bool second = (kbg >= D2);
    const __hip_bfloat16* Ab = second ? A2 : A1;
    const size_t rstride = second ? (size_t)NN * D2 : (size_t)D2;
    const int kbase = second ? (kbg - D2) : kbg;
#pragma unroll
    for (int q = 0; q < 4; ++q) {
      const int id = wv * 4 + q;
      const int mi = id & 7, ks = id >> 3;
      const int row = mi * 16 + l15;
      const int kk = ks * 32 + l4 * 8;
      async_load16(Ab + (size_t)row * rstride + kbase + kk, ldsA + id * 1024);
    }
#pragma unroll
    for (int q = 0; q < 4; ++q) {
      const int id = wv * 4 + q;
      const int ni = id & 7, ks = id >> 3;
      const int nn2 = ni * 16 + l15;
      const int kk = ks * 32 + l4 * 8;
      async_load16(Wt + (size_t)nn2 * K + kbg + kk, ldsW + id * 1024);
    }
    __syncthreads();
#pragma unroll
    for (int ks = 0; ks < 2; ++ks) {
      bf16x8_t Af[4], Bf[4];
#pragma unroll
      for (int a = 0; a < 4; ++a)
        Af[a] = *(const bf16x8_t*)(ldsA + ((ks * 8 + wr * 4 + a) << 10) + (lane << 4));
#pragma unroll
      for (int q = 0; q < 4; ++q)
        Bf[q] = *(const bf16x8_t*)(ldsW + ((ks * 8 + wc * 4 + q) << 10) + (lane << 4));
#pragma unroll
      for (int a = 0; a < 4; ++a)
#pragma unroll
        for (int q = 0; q < 4; ++q)
          acc[a][q] = __builtin_amdgcn_mfma_f32_16x16x32_bf16(Af[a], Bf[q],
                                                              acc[a][q], 0, 0, 0);
    }
    __syncthreads();
  }

  const size_t bi2 = (size_t)(b * NN + i);
  float uval[4];
#pragma unroll
  for (int q = 0; q < 4; ++q) uval[q] = u[bi2 * OC + wc * 64 + q * 16 + l15];
  const size_t obase = (bi2 * NN + j0) * OC;
  const size_t vbase = (size_t)(b * NN + j0) * OC;

  if (BF16OUT) {
    if (REDUCE && tid < 128) { smax[tid] = 0u; smin[tid] = 0x3f800000u; }
    __syncthreads();
    float lmx[4] = {0.f, 0.f, 0.f, 0.f};
    float lmn[4] = {1.f, 1.f, 1.f, 1.f};
#pragma unroll
    for (int a = 0; a < 4; ++a) {
      const int rowb = wr * 64 + a * 16 + l4 * 4;
#pragma unroll
      for (int r = 0; r < 4; ++r) {
        const int j = rowb + r;
        const bool excl = (j0 + j) == i;
#pragma unroll
        for (int q = 0; q < 4; ++q) {
          const int col = wc * 64 + q * 16 + l15;
          const float x = acc[a][q][r] + uval[q] + v[vbase + (size_t)j * OC + col];
          const float sg = sigf(x);
          *(uint16_t*)(lds + j * 272 + col * 2) = f2bf_rne(sg);
          if (REDUCE && !excl) {
            lmx[q] = fmaxf(lmx[q], sg);
            lmn[q] = fminf(lmn[q], sg);
          }
        }
      }
    }
    if (REDUCE) {
#pragma unroll
      for (int q = 0; q < 4; ++q) {
        const int col = wc * 64 + q * 16 + l15;
        atomicMax(&smax[col], __float_as_uint(lmx[q]));
        atomicMin(&smin[col], __float_as_uint(lmn[q]));
      }
    }
    __syncthreads();
    uint16_t* const outp = (uint16_t*)out;
#pragma unroll
    for (int ci = 0; ci < 8; ++ci) {
      const int chunk = ci * 256 + tid;
      const int row = chunk >> 4, off = chunk & 15;
      const uint4 val = *(const uint4*)(lds + row * 272 + off * 16);
      *(uint4*)(outp + obase + (size_t)row * OC + off * 8) = val;
    }
    if (REDUCE && tid < 128) {
      unsigned* const r2u = (unsigned*)r2n;
      atomicMax(&r2u[bi2 * 256 + tid], smax[tid]);
      atomicMin(&r2u[bi2 * 256 + 128 + tid], smin[tid]);
    }
  } else {
    float* const outp = (float*)out;
#pragma unroll
    for (int a = 0; a < 4; ++a) {
      const int rowb = wr * 64 + a * 16 + l4 * 4;
#pragma unroll
      for (int r = 0; r < 4; ++r) {
        const int j = rowb + r;
#pragma unroll
        for (int q = 0; q < 4; ++q) {
          const int col = wc * 64 + q * 16 + l15;
          const float x = acc[a][q][r] + uval[q] + v[vbase + (size_t)j * OC + col];
          outp[obase + (size_t)j * OC + col] = sigf(x);
        }
      }
    }
  }
}

// ---------------------------------------------------------------------------
extern "C" void kernel_launch(void* const* d_in, const int* in_sizes, int n_in,
                              void* d_out, int out_size, void* d_ws,
                              size_t ws_size, hipStream_t stream) {
  const float* x0 = (const float*)d_in[0];
  const float* x1 = (const float*)d_in[1];
  const float* x2 = (const float*)d_in[2];
  const float *Wp[3][3], *bp[3][3];
  for (int l = 0; l < 3; ++l)
    for (int o = 0; o < 3; ++o) {
      Wp[l][o] = (const float*)d_in[3 + l * 6 + o * 2];
      bp[l][o] = (const float*)d_in[3 + l * 6 + o * 2 + 1];
    }

  const size_t F2E = (size_t)NB * NN * NN * OC;
  const size_t X2E = (size_t)NB * NN * NN * 64;

  uint8_t* ws = (uint8_t*)d_ws;
  size_t off = 0;
  auto carve = [&](size_t bytes) -> uint8_t* {
    uint8_t* p = ws + off;
    off += (bytes + 255) & ~(size_t)255;
    return p;
  };
  float* f0a = (float*)carve((size_t)NB * OC * 4);
  float* f0b = (float*)carve((size_t)NB * OC * 4);
  float* f1a = (float*)carve((size_t)NB * NN * OC * 4);
  float* f1b = (float*)carve((size_t)NB * NN * OC * 4);
  float* r2b = (float*)carve((size_t)NB * NN * 256 * 4);
  float* r2c = (float*)carve((size_t)NB * NN * 256 * 4);
  float* uu  = (float*)carve((size_t)NB * NN * OC * 4);
  float* vv  = (float*)carve((size_t)NB * NN * OC * 4);
  uint16_t* Wt0 = (uint16_t*)carve((size_t)OC * 128 * 2);
  uint16_t* Wt1 = (uint16_t*)carve((size_t)OC * 256 * 2);
  uint16_t* Wt2 = (uint16_t*)carve((size_t)OC * 256 * 2);
  uint16_t* Bt0 = (uint16_t*)carve((size_t)384 * 256 * 2);
  uint16_t* Bt1 = (uint16_t*)carve((size_t)384 * 512 * 2);
  uint16_t* Bt2 = (uint16_t*)carve((size_t)384 * 512 * 2);
  uint16_t* g1bf0 = (uint16_t*)carve((size_t)NB * NN * 256 * 2);
  uint16_t* g1bf1 = (uint16_t*)carve((size_t)NB * NN * 512 * 2);
  uint16_t* g1bf2 = (uint16_t*)carve((size_t)NB * NN * 512 * 2);
  __hip_bfloat16* f2a = (__hip_bfloat16*)carve(F2E * 2);

  __hip_bfloat16* f2b;
  uint16_t* x2bf;
  if (ws_size >= off + F2E * 2) {
    f2b = (__hip_bfloat16*)carve(F2E * 2);
    x2bf = (uint16_t*)f2b;  // aliases f2b; dead before f2b becomes live
  } else {
    f2b = (__hip_bfloat16*)d_in[2];  // x2 fully consumed in layer 0
    x2bf = (uint16_t*)carve(X2E * 2);
  }

  float* out_f0 = (float*)d_out;
  float* out_f1 = out_f0 + (size_t)NB * OC;
  float* out_f2 = out_f1 + (size_t)NB * NN * OC;

  prep_all<<<2240, 256, 0, stream>>>(Wp[0][2], Wp[1][2], Wp[2][2], Wp[0][1],
                                     Wp[1][1], Wp[2][1], Wt0, Wt1, Wt2, Bt0,
                                     Bt1, Bt2);
  reduce2_l0_kernel<<<NB * NN, 256, 0, stream>>>(x2, x0, x1, g1bf0, x2bf, r2b);

  // ---- layer 0 (d0=32, d1=64, d2=64; KP=256) ----
  o0_kernel<32, 64, true><<<NB, 256, 0, stream>>>(x0, x1, Wp[0][0], bp[0][0],
                                                  f0a, g1bf1);
  small_gemm<256, true><<<48, 256, 0, stream>>>(g1bf0, Bt0, bp[0][1], bp[0][2],
                                                f1a, g1bf1, uu, vv);
  gemm2_kernel<64, __hip_bfloat16, true><<<NB * NN * 2, 256, 0, stream>>>(
      (const __hip_bfloat16*)x2bf, Wt0, uu, vv, f2a, r2b);
  conv_r2_kernel<true><<<NB * NN, 256, 0, stream>>>(r2b, g1bf1, r2c);

  // ---- layer 1 (all dims 128; KP=512) ----
  o0_kernel<128, 128, true><<<NB, 256, 0, stream>>>(f0a, f1a, Wp[1][0],
                                                    bp[1][0], f0b, g1bf2);
  small_gemm<512, true><<<48, 256, 0, stream>>>(g1bf1, Bt1, bp[1][1], bp[1][2],
                                                f1b, g1bf2, uu, vv);
  gemm2_kernel<128, __hip_bfloat16, true><<<NB * NN * 2, 256, 0, stream>>>(
      f2a, Wt1, uu, vv, f2b, r2c);
  conv_r2_kernel<false><<<NB * NN, 256, 0, stream>>>(r2c, g1bf2, nullptr);

  // ---- layer 2 (outputs straight to d_out) ----
  o0_kernel<128, 128, false><<<NB, 256, 0, stream>>>(f0b, f1b, Wp[2][0],
                                                     bp[2][0], out_f0, nullptr);
  small_gemm<512, false><<<48, 256, 0, stream>>>(g1bf2, Bt2, bp[2][1], bp[2][2],
                                                 out_f1, nullptr, uu, vv);
  gemm2_kernel<128, float, false><<<NB * NN * 2, 256, 0, stream>>>(
      f2b, Wt2, uu, vv, out_f2, nullptr);
}